// Round 5
// baseline (6334.126 us; speedup 1.0000x reference)
//
#include <hip/hip_runtime.h>
#include <hip/hip_bf16.h>

typedef __bf16 bf16x8 __attribute__((ext_vector_type(8)));
typedef float f32x4 __attribute__((ext_vector_type(4)));
typedef unsigned short u16;

#define GLD_LDS16(gp, lp) __builtin_amdgcn_global_load_lds( \
    (const __attribute__((address_space(1))) unsigned int*)(gp), \
    (__attribute__((address_space(3))) unsigned int*)(lp), 16, 0, 0)

__device__ __forceinline__ float tanh_fast(float x) {
  float e = __expf(2.0f * x);
  return 1.0f - __fdividef(2.0f, e + 1.0f);
}

__device__ __forceinline__ u16 bf16_rn(float x) {
  union { float f; unsigned u; } v; v.f = x;
  unsigned r = v.u + 0x7fffu + ((v.u >> 16) & 1u);
  return (u16)(r >> 16);
}

// ---------------------------------------------------------------------------
// Fused GEMM: C[M,N] = A[M,K] (bf16 row-major) x Bt[N,K]^T (bf16 row-major)
// m97 2-barrier structure, BK=128, 256 threads (4 waves 2x2), global_load_lds
// width-16 staging, 16x16x32 bf16 MFMA, XCD m-band swizzle (R4, proven).
// NEW (R5): LDS-staged vectorized epilogue — after the K loop the staging LDS
// is dead; stage C there in fragment layout, then a coalesced dwordx4 pass.
//   MODE 0: out_bf = bf16(tanh(acc + b1 + t*wt))          [stores 64x2B -> 8x16B]
//   MODE 1: v = 0.999*y + 0.001*z + h*(acc+b); out32=v, out_bf=v  [all 16B ops]
//   MODE 2: v = z + h*(acc+b);                 out32=v, out_bf=v
// ---------------------------------------------------------------------------
template <int BM, int BN, int K, int MODE, int NTL>
__global__ __launch_bounds__(256)
void gemm_fused(const u16* __restrict__ A, const u16* __restrict__ Bt,
                const float* __restrict__ bias, const float* __restrict__ wt,
                float tval,
                const float* __restrict__ y_in, const float* __restrict__ z_in,
                float* __restrict__ out32, u16* __restrict__ out_bf, int N) {
  constexpr int BK = 128;
  constexpr int WTM = BM / 2, WTN = BN / 2;   // per-wave tile (2x2 wave grid)
  constexpr int FM = WTM / 16, FN = WTN / 16; // fragments per wave
  constexpr int ACH = BM * BK * 2 / 1024;     // 1KB staging chunks
  constexpr int BCH = BN * BK * 2 / 1024;
  constexpr int CPH_A = BM / 8;               // chunks per half-K slab
  constexpr int CPH_B = BN / 8;
  constexpr int MT = 4096 / BM;               // m-tiles total
  constexpr int MPX = MT / 8;                 // m-tiles per XCD
  constexpr int ASZ = BM * 256;               // bytes: [2][BM][64] u16
  constexpr int BSZ = BN * 256;

  __shared__ __align__(16) char smem[ASZ + BSZ];
  u16* As = (u16*)smem;
  u16* Bs = (u16*)(smem + ASZ);

  // epilogue staging fits in the (dead) K-loop LDS
  static_assert(MODE != 0 || BM * 272 <= ASZ + BSZ, "mode0 staging");
  static_assert(MODE == 0 || BM * 288 <= ASZ + BSZ, "mode12 staging");

  const int tid = threadIdx.x;
  const int wave = tid >> 6;
  const int lane = tid & 63;
  const int wm = wave >> 1, wn = wave & 1;
  const int l15 = lane & 15, kg = lane >> 4;

  const int wg = blockIdx.x;
  const int xcd = wg & 7;
  const int j = wg >> 3;
  const int bm0 = (xcd * MPX + j / NTL) * BM;
  const int bn0 = (j % NTL) * BN;

  f32x4 acc[FM][FN];
#pragma unroll
  for (int m = 0; m < FM; ++m)
#pragma unroll
    for (int n = 0; n < FN; ++n) acc[m][n] = (f32x4){0.f, 0.f, 0.f, 0.f};

  const int sr = lane >> 3;       // row within 8-row (1KB) chunk
  const int sc = (lane & 7) * 8;  // element offset within 64-col half-row

  const u16* Ag = A + (size_t)bm0 * K;
  const u16* Bg = Bt + (size_t)bn0 * K;

  for (int kt = 0; kt < K / BK; ++kt) {
    const u16* Ak = Ag + kt * BK;
    const u16* Bk = Bg + kt * BK;
#pragma unroll
    for (int i = 0; i < ACH / 4; ++i) {
      const int ch = wave + i * 4;
      const int kh = ch / CPH_A;
      const int rg = ch % CPH_A;
      GLD_LDS16(Ak + (size_t)(rg * 8 + sr) * K + kh * 64 + sc,
                (char*)As + ch * 1024);
    }
#pragma unroll
    for (int i = 0; i < BCH / 4; ++i) {
      const int ch = wave + i * 4;
      const int kh = ch / CPH_B;
      const int rg = ch % CPH_B;
      GLD_LDS16(Bk + (size_t)(rg * 8 + sr) * K + kh * 64 + sc,
                (char*)Bs + ch * 1024);
    }
    __syncthreads();
#pragma unroll
    for (int ks = 0; ks < 4; ++ks) {
      const int kh = ks >> 1;
      const int kc = (ks & 1) * 32 + kg * 8;
      bf16x8 af[FM], bfr[FN];
#pragma unroll
      for (int m = 0; m < FM; ++m)
        af[m] = *reinterpret_cast<const bf16x8*>(
            &As[(kh * BM + wm * WTM + m * 16 + l15) * 64 + kc]);
#pragma unroll
      for (int n = 0; n < FN; ++n)
        bfr[n] = *reinterpret_cast<const bf16x8*>(
            &Bs[(kh * BN + wn * WTN + n * 16 + l15) * 64 + kc]);
#pragma unroll
      for (int m = 0; m < FM; ++m)
#pragma unroll
        for (int n = 0; n < FN; ++n)
          acc[m][n] =
              __builtin_amdgcn_mfma_f32_16x16x32_bf16(af[m], bfr[n], acc[m][n], 0, 0, 0);
    }
    __syncthreads();  // also fences LDS reads before epilogue reuse
  }

  // C/D layout (verified m89/m91): col = lane&15, row = (lane>>4)*4 + reg.
  const int r0 = wm * WTM + kg * 4;
  const int cb = wn * WTN + l15;

  if (MODE == 0) {
    // Stage bf16(tanh(.)) into padded [BM][136] u16 (row stride 272B).
    u16* st = (u16*)smem;
    u16* stp = st + r0 * 136 + cb;
#pragma unroll
    for (int n = 0; n < FN; ++n) {
      const int col = bn0 + cb + n * 16;
      const float bv = bias[col] + tval * wt[col];
#pragma unroll
      for (int m = 0; m < FM; ++m)
#pragma unroll
        for (int r = 0; r < 4; ++r)
          stp[(m * 16 + r) * 136 + n * 16] = bf16_rn(tanh_fast(acc[m][n][r] + bv));
    }
    __syncthreads();
    // Coalesced flush: each thread one 128B row-half, 8x(ds_read_b128+dwordx4).
    const int row = tid >> 1;
    const int c0 = (tid & 1) * 64;
    const char* lsrc = (const char*)st + row * 272 + c0 * 2;
    u16* gdst = out_bf + (size_t)(bm0 + row) * N + bn0 + c0;
#pragma unroll
    for (int i = 0; i < 8; ++i) {
      uint4 v = *reinterpret_cast<const uint4*>(lsrc + i * 16);
      *reinterpret_cast<uint4*>(gdst + i * 8) = v;
    }
  } else {
    // Stage acc+bias as f32 into padded [BM][72] f32 (row stride 288B).
    float* stf = (float*)smem;
    float* stp = stf + r0 * 72 + cb;
#pragma unroll
    for (int n = 0; n < FN; ++n) {
      const float bv = bias[bn0 + cb + n * 16];
#pragma unroll
      for (int m = 0; m < FM; ++m)
#pragma unroll
        for (int r = 0; r < 4; ++r)
          stp[(m * 16 + r) * 72 + n * 16] = acc[m][n][r] + bv;
    }
    __syncthreads();
    // Coalesced pass: row quarter per thread; y/z loads + both stores as 16B.
    const int row = tid >> 2;
    const int c0 = (tid & 3) * 16;
    const float* lsrc = stf + row * 72 + c0;
    const size_t gbase = (size_t)(bm0 + row) * N + bn0 + c0;
#pragma unroll
    for (int i = 0; i < 4; ++i) {
      const f32x4 a = *reinterpret_cast<const f32x4*>(lsrc + i * 4);
      f32x4 v;
      if (MODE == 1) {
        const f32x4 y4 = *reinterpret_cast<const f32x4*>(&y_in[gbase + i * 4]);
        const f32x4 z4 = *reinterpret_cast<const f32x4*>(&z_in[gbase + i * 4]);
#pragma unroll
        for (int q = 0; q < 4; ++q)
          v[q] = 0.999f * y4[q] + 0.001f * z4[q] + 0.015625f * a[q];
      } else {
        const f32x4 z4 = *reinterpret_cast<const f32x4*>(&z_in[gbase + i * 4]);
#pragma unroll
        for (int q = 0; q < 4; ++q) v[q] = z4[q] + 0.015625f * a[q];
      }
      *reinterpret_cast<f32x4*>(&out32[gbase + i * 4]) = v;
      ushort4 pb;
      pb.x = bf16_rn(v[0]); pb.y = bf16_rn(v[1]);
      pb.z = bf16_rn(v[2]); pb.w = bf16_rn(v[3]);
      *reinterpret_cast<ushort4*>(&out_bf[gbase + i * 4]) = pb;
    }
  }
}

// in: [R, C] f32  ->  out: [C, R] bf16
__global__ void transpose_bf16(const float* __restrict__ in, u16* __restrict__ out,
                               int R, int C) {
  __shared__ float tile[32][33];
  const int bx = blockIdx.x * 32;
  const int by = blockIdx.y * 32;
  const int tx = threadIdx.x, ty = threadIdx.y;  // 32 x 8
#pragma unroll
  for (int i = 0; i < 32; i += 8)
    tile[ty + i][tx] = in[(size_t)(by + ty + i) * C + (bx + tx)];
  __syncthreads();
#pragma unroll
  for (int i = 0; i < 32; i += 8)
    out[(size_t)(bx + ty + i) * R + (by + tx)] = bf16_rn(tile[tx][ty + i]);
}

__global__ void init_state(const float* __restrict__ y0, float* __restrict__ y32,
                           float* __restrict__ z32, u16* __restrict__ zbf, int n) {
  const int i = blockIdx.x * blockDim.x + threadIdx.x;
  if (i < n) {
    const float v = y0[i];
    y32[i] = v;
    z32[i] = v;
    zbf[i] = bf16_rn(v);
  }
}

extern "C" void kernel_launch(void* const* d_in, const int* in_sizes, int n_in,
                              void* d_out, int out_size, void* d_ws, size_t ws_size,
                              hipStream_t stream) {
  const float* y0 = (const float*)d_in[0];
  const float* W1 = (const float*)d_in[1];  // [512, 2048]
  const float* b1 = (const float*)d_in[2];  // [2048]
  const float* wt = (const float*)d_in[3];  // [2048]
  const float* W2 = (const float*)d_in[4];  // [2048, 512]
  const float* b2 = (const float*)d_in[5];  // [512]

  constexpr int B = 4096, D = 512, HID = 2048, NSTEP = 64;
  constexpr float Hh = 1.0f / 64.0f;

  char* ws = (char*)d_ws;
  u16* W1t = (u16*)ws; ws += (size_t)HID * D * 2;   // [2048][512] bf16
  u16* W2t = (u16*)ws; ws += (size_t)D * HID * 2;   // [512][2048] bf16
  u16* hid = (u16*)ws; ws += (size_t)B * HID * 2;   // [4096][2048] bf16
  float* z32 = (float*)ws; ws += (size_t)B * D * 4; // [4096][512] f32
  u16* ybf = (u16*)ws; ws += (size_t)B * D * 2;
  u16* zbf = (u16*)ws; ws += (size_t)B * D * 2;
  float* y32 = (float*)d_out;

  transpose_bf16<<<dim3(HID / 32, D / 32), dim3(32, 8), 0, stream>>>(W1, W1t, D, HID);
  transpose_bf16<<<dim3(D / 32, HID / 32), dim3(32, 8), 0, stream>>>(W2, W2t, HID, D);
  init_state<<<(B * D + 255) / 256, 256, 0, stream>>>(y0, y32, z32, zbf, B * D);

  for (int s = 0; s < NSTEP; ++s) {
    const float t0 = (float)s * Hh;
    const float t1 = (float)(s + 1) * Hh;
    // hidden = tanh(z @ W1 + b1 + t0*wt)   512 blocks (32 m-tiles x 16 n-tiles)
    gemm_fused<128, 128, 512, 0, 16><<<512, 256, 0, stream>>>(
        zbf, W1t, b1, wt, t0, nullptr, nullptr, nullptr, hid, HID);
    // y = 0.999*y + 0.001*z + h*(hidden @ W2 + b2)   512 blocks (64 x 8)
    gemm_fused<64, 64, 2048, 1, 8><<<512, 256, 0, stream>>>(
        hid, W2t, b2, nullptr, 0.f, y32, z32, y32, ybf, D);
    // hidden = tanh(y @ W1 + b1 + t1*wt)
    gemm_fused<128, 128, 512, 0, 16><<<512, 256, 0, stream>>>(
        ybf, W1t, b1, wt, t1, nullptr, nullptr, nullptr, hid, HID);
    // z = z + h*(hidden @ W2 + b2)
    gemm_fused<64, 64, 2048, 2, 8><<<512, 256, 0, stream>>>(
        hid, W2t, b2, nullptr, 0.f, nullptr, z32, z32, zbf, D);
  }
}

// Round 6
// 5161.148 us; speedup vs baseline: 1.2273x; 1.2273x over previous
//
#include <hip/hip_runtime.h>
#include <hip/hip_bf16.h>

typedef __bf16 bf16x8 __attribute__((ext_vector_type(8)));
typedef float f32x4 __attribute__((ext_vector_type(4)));
typedef unsigned short u16;

#define GLD_LDS16(gp, lp) __builtin_amdgcn_global_load_lds( \
    (const __attribute__((address_space(1))) unsigned int*)(gp), \
    (__attribute__((address_space(3))) unsigned int*)(lp), 16, 0, 0)

__device__ __forceinline__ float tanh_fast(float x) {
  float e = __expf(2.0f * x);
  return 1.0f - __fdividef(2.0f, e + 1.0f);
}

__device__ __forceinline__ u16 bf16_rn(float x) {
  union { float f; unsigned u; } v; v.f = x;
  unsigned r = v.u + 0x7fffu + ((v.u >> 16) & 1u);
  return (u16)(r >> 16);
}

// ---------------------------------------------------------------------------
// Fused GEMM: C[M,N] = A[M,K] (bf16 row-major) x Bt[N,K]^T (bf16 row-major)
// m97 2-barrier structure, templated BK (NS = BK/64 half-K slabs so the LDS
// row stride stays 128B -> same verified bank pattern), 256 threads (4 waves
// 2x2), global_load_lds width-16 staging, 16x16x32 bf16 MFMA, XCD m-band
// swizzle (writer and reader use the same band map -> hid stays in-XCD L2).
//   GEMM-A: 128x128, BK=128 (R4-proven; BK=256 would cost a block/CU of LDS)
//   GEMM-B:  64x64,  BK=256 (R6: halve barrier-drains again; 64KB LDS still
//            2 blocks/CU at grid=512)
// Epilogue: direct fragment-layout stores (R4 version; R5's LDS-staged
// epilogue regressed +13% -- the LDS round-trip cost more than it saved).
// MODE 0: out_bf = bf16(tanh(acc + bias + t*wt))
// MODE 1: v = 0.999*y + 0.001*z + h*(acc+bias); out32 = v; out_bf = v
// MODE 2: v = z + h*(acc+bias);                 out32 = v; out_bf = v
// ---------------------------------------------------------------------------
template <int BM, int BN, int BK, int K, int MODE, int NTL>
__global__ __launch_bounds__(256)
void gemm_fused(const u16* __restrict__ A, const u16* __restrict__ Bt,
                const float* __restrict__ bias, const float* __restrict__ wt,
                float tval,
                const float* __restrict__ y_in, const float* __restrict__ z_in,
                float* __restrict__ out32, u16* __restrict__ out_bf, int N) {
  constexpr int NS = BK / 64;                 // half-K slabs
  constexpr int WTM = BM / 2, WTN = BN / 2;   // per-wave tile (2x2 wave grid)
  constexpr int FM = WTM / 16, FN = WTN / 16; // fragments per wave
  constexpr int ACH = BM * BK * 2 / 1024;     // 1KB staging chunks
  constexpr int BCH = BN * BK * 2 / 1024;
  constexpr int CPS_A = BM / 8;               // chunks per slab
  constexpr int CPS_B = BN / 8;
  constexpr int MT = 4096 / BM;               // m-tiles total
  constexpr int MPX = MT / 8;                 // m-tiles per XCD

  __shared__ u16 As[NS * BM * 64];  // [slab][row][64]
  __shared__ u16 Bs[NS * BN * 64];

  const int tid = threadIdx.x;
  const int wave = tid >> 6;
  const int lane = tid & 63;
  const int wm = wave >> 1, wn = wave & 1;
  const int l15 = lane & 15, kg = lane >> 4;

  const int wg = blockIdx.x;
  const int xcd = wg & 7;
  const int j = wg >> 3;
  const int bm0 = (xcd * MPX + j / NTL) * BM;
  const int bn0 = (j % NTL) * BN;

  f32x4 acc[FM][FN];
#pragma unroll
  for (int m = 0; m < FM; ++m)
#pragma unroll
    for (int n = 0; n < FN; ++n) acc[m][n] = (f32x4){0.f, 0.f, 0.f, 0.f};

  const int sr = lane >> 3;       // row within 8-row (1KB) chunk
  const int sc = (lane & 7) * 8;  // element offset within 64-col half-row

  const u16* Ag = A + (size_t)bm0 * K;
  const u16* Bg = Bt + (size_t)bn0 * K;

  for (int kt = 0; kt < K / BK; ++kt) {
    const u16* Ak = Ag + kt * BK;
    const u16* Bk = Bg + kt * BK;
#pragma unroll
    for (int i = 0; i < ACH / 4; ++i) {
      const int ch = wave + i * 4;
      const int kh = ch / CPS_A;   // slab index
      const int rg = ch % CPS_A;   // 8-row group
      GLD_LDS16(Ak + (size_t)(rg * 8 + sr) * K + kh * 64 + sc,
                (char*)As + ch * 1024);
    }
#pragma unroll
    for (int i = 0; i < BCH / 4; ++i) {
      const int ch = wave + i * 4;
      const int kh = ch / CPS_B;
      const int rg = ch % CPS_B;
      GLD_LDS16(Bk + (size_t)(rg * 8 + sr) * K + kh * 64 + sc,
                (char*)Bs + ch * 1024);
    }
    __syncthreads();
#pragma unroll
    for (int ks = 0; ks < 2 * NS; ++ks) {
      const int kh = ks >> 1;
      const int kc = (ks & 1) * 32 + kg * 8;
      bf16x8 af[FM], bfr[FN];
#pragma unroll
      for (int m = 0; m < FM; ++m)
        af[m] = *reinterpret_cast<const bf16x8*>(
            &As[(kh * BM + wm * WTM + m * 16 + l15) * 64 + kc]);
#pragma unroll
      for (int n = 0; n < FN; ++n)
        bfr[n] = *reinterpret_cast<const bf16x8*>(
            &Bs[(kh * BN + wn * WTN + n * 16 + l15) * 64 + kc]);
#pragma unroll
      for (int m = 0; m < FM; ++m)
#pragma unroll
        for (int n = 0; n < FN; ++n)
          acc[m][n] =
              __builtin_amdgcn_mfma_f32_16x16x32_bf16(af[m], bfr[n], acc[m][n], 0, 0, 0);
    }
    __syncthreads();
  }

  // Epilogue (R4 direct stores). C/D layout: col = lane&15, row = (lane>>4)*4 + reg.
#pragma unroll
  for (int n = 0; n < FN; ++n) {
    const int col = bn0 + wn * WTN + n * 16 + l15;
    const float bv = bias[col];
    const float wv = (MODE == 0) ? wt[col] : 0.f;
#pragma unroll
    for (int m = 0; m < FM; ++m) {
      const int row0 = bm0 + wm * WTM + m * 16 + kg * 4;
#pragma unroll
      for (int r = 0; r < 4; ++r) {
        const size_t idx = (size_t)(row0 + r) * N + col;
        const float a = acc[m][n][r];
        if (MODE == 0) {
          const float x = a + bv + tval * wv;
          out_bf[idx] = bf16_rn(tanh_fast(x));
        } else if (MODE == 1) {
          const float v = 0.999f * y_in[idx] + 0.001f * z_in[idx] +
                          0.015625f * (a + bv);
          out32[idx] = v;
          out_bf[idx] = bf16_rn(v);
        } else {
          const float v = z_in[idx] + 0.015625f * (a + bv);
          out32[idx] = v;
          out_bf[idx] = bf16_rn(v);
        }
      }
    }
  }
}

// in: [R, C] f32  ->  out: [C, R] bf16
__global__ void transpose_bf16(const float* __restrict__ in, u16* __restrict__ out,
                               int R, int C) {
  __shared__ float tile[32][33];
  const int bx = blockIdx.x * 32;
  const int by = blockIdx.y * 32;
  const int tx = threadIdx.x, ty = threadIdx.y;  // 32 x 8
#pragma unroll
  for (int i = 0; i < 32; i += 8)
    tile[ty + i][tx] = in[(size_t)(by + ty + i) * C + (bx + tx)];
  __syncthreads();
#pragma unroll
  for (int i = 0; i < 32; i += 8)
    out[(size_t)(bx + ty + i) * R + (by + tx)] = bf16_rn(tile[tx][ty + i]);
}

__global__ void init_state(const float* __restrict__ y0, float* __restrict__ y32,
                           float* __restrict__ z32, u16* __restrict__ zbf, int n) {
  const int i = blockIdx.x * blockDim.x + threadIdx.x;
  if (i < n) {
    const float v = y0[i];
    y32[i] = v;
    z32[i] = v;
    zbf[i] = bf16_rn(v);
  }
}

extern "C" void kernel_launch(void* const* d_in, const int* in_sizes, int n_in,
                              void* d_out, int out_size, void* d_ws, size_t ws_size,
                              hipStream_t stream) {
  const float* y0 = (const float*)d_in[0];
  const float* W1 = (const float*)d_in[1];  // [512, 2048]
  const float* b1 = (const float*)d_in[2];  // [2048]
  const float* wt = (const float*)d_in[3];  // [2048]
  const float* W2 = (const float*)d_in[4];  // [2048, 512]
  const float* b2 = (const float*)d_in[5];  // [512]

  constexpr int B = 4096, D = 512, HID = 2048, NSTEP = 64;
  constexpr float Hh = 1.0f / 64.0f;

  char* ws = (char*)d_ws;
  u16* W1t = (u16*)ws; ws += (size_t)HID * D * 2;   // [2048][512] bf16
  u16* W2t = (u16*)ws; ws += (size_t)D * HID * 2;   // [512][2048] bf16
  u16* hid = (u16*)ws; ws += (size_t)B * HID * 2;   // [4096][2048] bf16
  float* z32 = (float*)ws; ws += (size_t)B * D * 4; // [4096][512] f32
  u16* ybf = (u16*)ws; ws += (size_t)B * D * 2;
  u16* zbf = (u16*)ws; ws += (size_t)B * D * 2;
  float* y32 = (float*)d_out;

  transpose_bf16<<<dim3(HID / 32, D / 32), dim3(32, 8), 0, stream>>>(W1, W1t, D, HID);
  transpose_bf16<<<dim3(D / 32, HID / 32), dim3(32, 8), 0, stream>>>(W2, W2t, HID, D);
  init_state<<<(B * D + 255) / 256, 256, 0, stream>>>(y0, y32, z32, zbf, B * D);

  for (int s = 0; s < NSTEP; ++s) {
    const float t0 = (float)s * Hh;
    const float t1 = (float)(s + 1) * Hh;
    // hidden = tanh(z @ W1 + b1 + t0*wt)   512 blocks (32 m-tiles x 16 n-tiles)
    gemm_fused<128, 128, 128, 512, 0, 16><<<512, 256, 0, stream>>>(
        zbf, W1t, b1, wt, t0, nullptr, nullptr, nullptr, hid, HID);
    // y = 0.999*y + 0.001*z + h*(hidden @ W2 + b2)   512 blocks (64 x 8)
    gemm_fused<64, 64, 256, 2048, 1, 8><<<512, 256, 0, stream>>>(
        hid, W2t, b2, nullptr, 0.f, y32, z32, y32, ybf, D);
    // hidden = tanh(y @ W1 + b1 + t1*wt)
    gemm_fused<128, 128, 128, 512, 0, 16><<<512, 256, 0, stream>>>(
        ybf, W1t, b1, wt, t1, nullptr, nullptr, nullptr, hid, HID);
    // z = z + h*(hidden @ W2 + b2)
    gemm_fused<64, 64, 256, 2048, 2, 8><<<512, 256, 0, stream>>>(
        hid, W2t, b2, nullptr, 0.f, nullptr, z32, z32, zbf, D);
  }
}